// Round 1
// baseline (1247.956 us; speedup 1.0000x reference)
//
#include <hip/hip_runtime.h>

#define C_IN 256
#define C_OUT 64

// ---------------- degree kernels ----------------
__global__ void k_init_deg(float* __restrict__ deg, int n) {
    int i = blockIdx.x * blockDim.x + threadIdx.x;
    if (i < n) deg[i] = 1.0f;  // self-loop
}

__global__ void k_count_deg(const int* __restrict__ dst, float* __restrict__ deg, int e) {
    int i = blockIdx.x * blockDim.x + threadIdx.x;
    if (i < e) atomicAdd(&deg[dst[i]], 1.0f);
}

__global__ void k_rsqrt_deg(float* __restrict__ deg, int n) {
    int i = blockIdx.x * blockDim.x + threadIdx.x;
    if (i < n) deg[i] = rsqrtf(deg[i]);  // deg >= 1 always (self-loop)
}

// ---------------- h = x @ W ----------------
// Block = 256 threads. Each thread: 4 rows x 4 channels register tile.
// Rows per block = (256/16 groups) * 4 = 64. W staged in LDS (64 KB).
__global__ __launch_bounds__(256) void k_gemm(const float* __restrict__ x,
                                              const float* __restrict__ W,
                                              float* __restrict__ h, int n) {
    __shared__ float Wl[C_IN * C_OUT];
    {
        const float4* Wv  = (const float4*)W;
        float4*       Wlv = (float4*)Wl;
        for (int i = threadIdx.x; i < C_IN * C_OUT / 4; i += 256) Wlv[i] = Wv[i];
    }
    __syncthreads();

    const int t  = threadIdx.x;
    const int cb = (t & 15) * 4;                  // channel base 0..60
    const int r0 = blockIdx.x * 64 + (t >> 4) * 4; // row base

    float4 acc[4];
    for (int j = 0; j < 4; ++j) acc[j] = make_float4(0.f, 0.f, 0.f, 0.f);

    for (int k = 0; k < C_IN; k += 4) {
        float4 xv[4];
        for (int j = 0; j < 4; ++j) {
            int r = r0 + j;
            xv[j] = (r < n) ? *(const float4*)&x[(size_t)r * C_IN + k]
                            : make_float4(0.f, 0.f, 0.f, 0.f);
        }
#pragma unroll
        for (int kk = 0; kk < 4; ++kk) {
            float4 wv = *(const float4*)&Wl[(k + kk) * C_OUT + cb];
            float xs;
#pragma unroll
            for (int j = 0; j < 4; ++j) {
                xs = (kk == 0) ? xv[j].x : (kk == 1) ? xv[j].y : (kk == 2) ? xv[j].z : xv[j].w;
                acc[j].x += xs * wv.x;
                acc[j].y += xs * wv.y;
                acc[j].z += xs * wv.z;
                acc[j].w += xs * wv.w;
            }
        }
    }
    for (int j = 0; j < 4; ++j) {
        int r = r0 + j;
        if (r < n) *(float4*)&h[(size_t)r * C_OUT + cb] = acc[j];
    }
}

// ---------------- out = h * dinv^2 + b (self-loop term + bias) ----------------
__global__ void k_init_out(const float* __restrict__ h, const float* __restrict__ dinv,
                           const float* __restrict__ b, float* __restrict__ out, int n) {
    int i = blockIdx.x * blockDim.x + threadIdx.x;
    if (i < n * C_OUT) {
        int node = i >> 6;
        int c    = i & 63;
        float s  = dinv[node];
        out[i] = h[i] * s * s + b[c];
    }
}

// ---------------- edge scatter: out[dst] += h[src] * dinv[src]*dinv[dst] ----------------
// One wave (64 lanes) per edge; lane == output channel.
__global__ __launch_bounds__(256) void k_edge(const int* __restrict__ src,
                                              const int* __restrict__ dst,
                                              const float* __restrict__ h,
                                              const float* __restrict__ dinv,
                                              float* __restrict__ out, int e) {
    int eid = blockIdx.x * 4 + (threadIdx.x >> 6);
    if (eid >= e) return;
    int c = threadIdx.x & 63;
    int s = src[eid];
    int d = dst[eid];
    float norm = dinv[s] * dinv[d];
    atomicAdd(&out[(size_t)d * C_OUT + c], h[(size_t)s * C_OUT + c] * norm);
}

extern "C" void kernel_launch(void* const* d_in, const int* in_sizes, int n_in,
                              void* d_out, int out_size, void* d_ws, size_t ws_size,
                              hipStream_t stream) {
    const float* x  = (const float*)d_in[0];
    const int*   ei = (const int*)d_in[1];
    const float* W  = (const float*)d_in[2];
    const float* b  = (const float*)d_in[3];
    float*       out = (float*)d_out;

    const int n = in_sizes[0] / C_IN;   // 100000
    const int e = in_sizes[1] / 2;      // 3200000
    const int* src = ei;                // edge_index[0]
    const int* dst = ei + e;            // edge_index[1]

    float* ws   = (float*)d_ws;
    float* h    = ws;                   // n * 64 floats
    float* dinv = ws + (size_t)n * C_OUT; // n floats (deg, then rsqrt in place)

    // degree (incl. self-loops) -> dinv
    k_init_deg<<<(n + 255) / 256, 256, 0, stream>>>(dinv, n);
    k_count_deg<<<(e + 255) / 256, 256, 0, stream>>>(dst, dinv, e);
    k_rsqrt_deg<<<(n + 255) / 256, 256, 0, stream>>>(dinv, n);

    // h = x @ W
    k_gemm<<<(n + 63) / 64, 256, 0, stream>>>(x, W, h, n);

    // out = self-loop term + bias
    k_init_out<<<((size_t)n * C_OUT + 255) / 256, 256, 0, stream>>>(h, dinv, b, out, n);

    // edge scatter
    k_edge<<<(e + 3) / 4, 256, 0, stream>>>(src, dst, h, dinv, out, e);
}

// Round 2
// 951.729 us; speedup vs baseline: 1.3113x; 1.3113x over previous
//
#include <hip/hip_runtime.h>

#define C_IN 256
#define C_OUT 64
#define SCAN_B 256   // elems per scan block

// ---------------- degree: int histogram ----------------
__global__ void k_zero(int* __restrict__ p, int n) {
    int i = blockIdx.x * blockDim.x + threadIdx.x;
    if (i < n) p[i] = 0;
}

__global__ void k_count(const int* __restrict__ dst, int* __restrict__ deg, int e) {
    int i = blockIdx.x * blockDim.x + threadIdx.x;
    if (i < e) atomicAdd(&deg[dst[i]], 1);
}

// ---------------- exclusive scan (3 kernels) ----------------
__global__ void k_scan1(const int* __restrict__ deg, int* __restrict__ rowptr,
                        int* __restrict__ aux, int n) {
    __shared__ int l[SCAN_B];
    int i = blockIdx.x * SCAN_B + threadIdx.x;
    int v = (i < n) ? deg[i] : 0;
    l[threadIdx.x] = v;
    __syncthreads();
    for (int off = 1; off < SCAN_B; off <<= 1) {
        int t = (threadIdx.x >= off) ? l[threadIdx.x - off] : 0;
        __syncthreads();
        l[threadIdx.x] += t;
        __syncthreads();
    }
    if (i < n) rowptr[i] = l[threadIdx.x] - v;  // exclusive, pre-block-offset
    if (threadIdx.x == SCAN_B - 1) aux[blockIdx.x] = l[SCAN_B - 1];
}

__global__ void k_scan2(int* __restrict__ aux, int nb) {  // nb <= 512
    __shared__ int l[512];
    int v = (threadIdx.x < nb) ? aux[threadIdx.x] : 0;
    l[threadIdx.x] = v;
    __syncthreads();
    for (int off = 1; off < 512; off <<= 1) {
        int t = (threadIdx.x >= off) ? l[threadIdx.x - off] : 0;
        __syncthreads();
        l[threadIdx.x] += t;
        __syncthreads();
    }
    if (threadIdx.x < nb) aux[threadIdx.x] = l[threadIdx.x] - v;  // exclusive
}

__global__ void k_scan3(int* __restrict__ rowptr, const int* __restrict__ aux,
                        int* __restrict__ cursor, const int* __restrict__ deg,
                        float* __restrict__ dinv, int n, int e) {
    int i = blockIdx.x * SCAN_B + threadIdx.x;
    if (i < n) {
        int r = rowptr[i] + aux[blockIdx.x];
        rowptr[i] = r;
        cursor[i] = r;
        dinv[i] = rsqrtf((float)(deg[i] + 1));  // +1 self-loop
    }
    if (i == 0) rowptr[n] = e;
}

// ---------------- CSR fill ----------------
__global__ void k_fill(const int* __restrict__ src, const int* __restrict__ dst,
                       int* __restrict__ cursor, int* __restrict__ eidx, int e) {
    int i = blockIdx.x * blockDim.x + threadIdx.x;
    if (i < e) {
        int pos = atomicAdd(&cursor[dst[i]], 1);
        eidx[pos] = src[i];
    }
}

// ---------------- h = x @ W ----------------
__global__ __launch_bounds__(256) void k_gemm(const float* __restrict__ x,
                                              const float* __restrict__ W,
                                              float* __restrict__ h, int n) {
    __shared__ float Wl[C_IN * C_OUT];
    {
        const float4* Wv  = (const float4*)W;
        float4*       Wlv = (float4*)Wl;
        for (int i = threadIdx.x; i < C_IN * C_OUT / 4; i += 256) Wlv[i] = Wv[i];
    }
    __syncthreads();

    const int t  = threadIdx.x;
    const int cb = (t & 15) * 4;
    const int r0 = blockIdx.x * 64 + (t >> 4) * 4;

    float4 acc[4];
    for (int j = 0; j < 4; ++j) acc[j] = make_float4(0.f, 0.f, 0.f, 0.f);

    for (int k = 0; k < C_IN; k += 4) {
        float4 xv[4];
        for (int j = 0; j < 4; ++j) {
            int r = r0 + j;
            xv[j] = (r < n) ? *(const float4*)&x[(size_t)r * C_IN + k]
                            : make_float4(0.f, 0.f, 0.f, 0.f);
        }
#pragma unroll
        for (int kk = 0; kk < 4; ++kk) {
            float4 wv = *(const float4*)&Wl[(k + kk) * C_OUT + cb];
#pragma unroll
            for (int j = 0; j < 4; ++j) {
                float xs = (kk == 0) ? xv[j].x : (kk == 1) ? xv[j].y : (kk == 2) ? xv[j].z : xv[j].w;
                acc[j].x += xs * wv.x;
                acc[j].y += xs * wv.y;
                acc[j].z += xs * wv.z;
                acc[j].w += xs * wv.w;
            }
        }
    }
    for (int j = 0; j < 4; ++j) {
        int r = r0 + j;
        if (r < n) *(float4*)&h[(size_t)r * C_OUT + cb] = acc[j];
    }
}

// ---------------- gather: one wave per node, lane = channel ----------------
__global__ __launch_bounds__(256) void k_gather(const int* __restrict__ rowptr,
                                                const int* __restrict__ eidx,
                                                const float* __restrict__ h,
                                                const float* __restrict__ dinv,
                                                const float* __restrict__ b,
                                                float* __restrict__ out, int n) {
    int node = blockIdx.x * 4 + (threadIdx.x >> 6);
    if (node >= n) return;
    int c = threadIdx.x & 63;

    int beg = rowptr[node];
    int end = rowptr[node + 1];
    float di = dinv[node];
    float acc = h[(size_t)node * C_OUT + c] * di * di + b[c];

    int j = beg;
    for (; j + 1 < end; j += 2) {
        int s0 = __builtin_amdgcn_readfirstlane(eidx[j]);
        int s1 = __builtin_amdgcn_readfirstlane(eidx[j + 1]);
        float n0 = dinv[s0] * di;
        float n1 = dinv[s1] * di;
        float v0 = h[(size_t)s0 * C_OUT + c];
        float v1 = h[(size_t)s1 * C_OUT + c];
        acc += v0 * n0;
        acc += v1 * n1;
    }
    if (j < end) {
        int s0 = __builtin_amdgcn_readfirstlane(eidx[j]);
        acc += h[(size_t)s0 * C_OUT + c] * (dinv[s0] * di);
    }
    out[(size_t)node * C_OUT + c] = acc;
}

extern "C" void kernel_launch(void* const* d_in, const int* in_sizes, int n_in,
                              void* d_out, int out_size, void* d_ws, size_t ws_size,
                              hipStream_t stream) {
    const float* x  = (const float*)d_in[0];
    const int*   ei = (const int*)d_in[1];
    const float* W  = (const float*)d_in[2];
    const float* b  = (const float*)d_in[3];
    float*       out = (float*)d_out;

    const int n = in_sizes[0] / C_IN;   // 100000
    const int e = in_sizes[1] / 2;      // 3200000
    const int* src = ei;
    const int* dst = ei + e;

    // workspace layout (all 4-byte aligned)
    char* w = (char*)d_ws;
    float* h      = (float*)w;                 w += (size_t)n * C_OUT * 4;  // 25.6 MB
    float* dinv   = (float*)w;                 w += (size_t)n * 4;
    int*   deg    = (int*)w;                   w += (size_t)n * 4;
    int*   rowptr = (int*)w;                   w += (size_t)(n + 1) * 4;
    int*   cursor = (int*)w;                   w += (size_t)n * 4;
    int*   aux    = (int*)w;                   w += 512 * 4;
    int*   eidx   = (int*)w;                   w += (size_t)e * 4;          // 12.8 MB

    const int nb = (n + SCAN_B - 1) / SCAN_B;  // 391

    k_zero<<<(n + 255) / 256, 256, 0, stream>>>(deg, n);
    k_count<<<(e + 255) / 256, 256, 0, stream>>>(dst, deg, e);
    k_scan1<<<nb, SCAN_B, 0, stream>>>(deg, rowptr, aux, n);
    k_scan2<<<1, 512, 0, stream>>>(aux, nb);
    k_scan3<<<nb, SCAN_B, 0, stream>>>(rowptr, aux, cursor, deg, dinv, n, e);
    k_fill<<<(e + 255) / 256, 256, 0, stream>>>(src, dst, cursor, eidx, e);
    k_gemm<<<(n + 63) / 64, 256, 0, stream>>>(x, W, h, n);
    k_gather<<<(n + 3) / 4, 256, 0, stream>>>(rowptr, eidx, h, dinv, b, out, n);
}